// Round 23
// baseline (99.636 us; speedup 1.0000x reference)
//
#include <hip/hip_runtime.h>
#include <stdint.h>

#define N_B 2
#define T_SEQ 2048
#define D_MODEL 1024
#define N_HEADS 16
#define HEAD_W 64

typedef __attribute__((ext_vector_type(8))) short short8;
typedef __attribute__((ext_vector_type(4))) float f32x4;

// async global->LDS, 16B per lane; LDS dst is wave-uniform base (HW adds lane*16)
#define GLOAD_LDS16(gp, lp)                                                          \
    __builtin_amdgcn_global_load_lds((__attribute__((address_space(1))) void*)(gp),  \
                                     (__attribute__((address_space(3))) void*)(lp),  \
                                     16, 0, 0)

__device__ __forceinline__ unsigned short f2bf(float f) {
    union { float f; uint32_t u; } cv; cv.f = f;
    return (unsigned short)((cv.u + 0x7fffu + ((cv.u >> 16) & 1u)) >> 16);  // RNE
}

__device__ __forceinline__ uint32_t cvt_pk_bf16(float lo, float hi) {
    uint32_t r;
    asm("v_cvt_pk_bf16_f32 %0, %1, %2" : "=v"(r) : "v"(lo), "v"(hi));
    return r;
}

__device__ __forceinline__ float bf2f(uint32_t us) {
    union { uint32_t u; float f; } cv; cv.u = us << 16; return cv.f;
}

#define LOG2E 1.44269504f

// ---------------- fused f32 -> bf16 converts (x, Wq*scale, Wk, Wv) ----------------
__global__ __launch_bounds__(256) void cvt_fused(const float4* __restrict__ x,
                                                 const float4* __restrict__ wq,
                                                 const float4* __restrict__ wk,
                                                 const float4* __restrict__ wv,
                                                 uint64_t* __restrict__ xb,
                                                 uint64_t* __restrict__ wqb,
                                                 uint64_t* __restrict__ wkb,
                                                 uint64_t* __restrict__ wvb) {
    const int i = blockIdx.x * 256 + threadIdx.x;   // 1835008 total float4s
    const float4* src; uint64_t* dst; float scale; int off;
    if (i < 1048576)      { src = x;  dst = xb;  scale = 1.f;            off = i; }
    else if (i < 1310720) { src = wq; dst = wqb; scale = 0.125f * LOG2E; off = i - 1048576; }
    else if (i < 1572864) { src = wk; dst = wkb; scale = 1.f;            off = i - 1310720; }
    else                  { src = wv; dst = wvb; scale = 1.f;            off = i - 1572864; }
    float4 v = src[off];
    union { unsigned short us[4]; uint64_t u64; } o;
    o.us[0] = f2bf(v.x * scale);
    o.us[1] = f2bf(v.y * scale);
    o.us[2] = f2bf(v.z * scale);
    o.us[3] = f2bf(v.w * scale);
    dst[off] = o.u64;
}

// ---------------- QKV projection GEMM (flattened grid + XCD swizzle, BK=64) ----------------
// C[m,n] = sum_k A[m,k]*W[n,k]   [proven 128x128 tile; (256,4) = 4 blocks/CU, R18/R19]
// All three outputs use the per-wave LDS bounce -> coalesced 16B stores:
// z=0: Q -> [b,h,t,w]; z=1: K -> [b,h,t,w]; z=2: V -> [b,h,w,t] (transposed)
__global__ __launch_bounds__(256, 4) void qkv_gemm(const unsigned short* __restrict__ A,
                                                   const unsigned short* __restrict__ W0,
                                                   const unsigned short* __restrict__ W1,
                                                   const unsigned short* __restrict__ W2,
                                                   unsigned short* __restrict__ O0,
                                                   unsigned short* __restrict__ O1,
                                                   unsigned short* __restrict__ O2) {
    __shared__ union {
        struct { unsigned short A[128 * 64]; unsigned short W[128 * 64]; } st;
        unsigned short vb[4][64 * 72];   // epilogue bounce (padded rows, 144B)
    } sh;
    // XCD-aware bijective swizzle: each XCD sweeps one column of tiles (W-panel L2-resident)
    const int bid0 = blockIdx.x;                       // 768 blocks
    const int bid = (bid0 & 7) * 96 + (bid0 >> 3);     // bijective: 768 = 8*96
    const int z = bid >> 8;
    const int rem = bid & 255;
    const int m0 = (rem >> 3) * 128;
    const int n0 = (rem & 7) * 128;
    const unsigned short* W = (z == 0) ? W0 : (z == 1) ? W1 : W2;
    const int tid = threadIdx.x;
    const int lane = tid & 63;
    const int ww = tid >> 6;
    const int wr = (ww >> 1) * 64;
    const int wc = (ww & 1) * 64;
    const int g = lane >> 4;             // k-granule 0..3 within 32-k chunk
    const int fr = lane & 15;
    const int srow = lane >> 3;          // staging row-in-chunk 0..7 (8 rows x 128B per 1KB)
    const int sgr = (lane & 7) ^ srow;   // pre-swizzled source granule (granule ^= row&7)

    f32x4 acc[4][4];
#pragma unroll
    for (int i = 0; i < 4; ++i)
#pragma unroll
        for (int j = 0; j < 4; ++j) acc[i][j] = (f32x4){0.f, 0.f, 0.f, 0.f};

    for (int k0 = 0; k0 < D_MODEL; k0 += 64) {
#pragma unroll
        for (int it = 0; it < 4; ++it) {
            const int chunk = ww * 4 + it;          // 0..15, each 8 rows x 64 shorts
            const int row = chunk * 8 + srow;       // 0..127
            GLOAD_LDS16(A + (size_t)(m0 + row) * D_MODEL + k0 + sgr * 8,
                        (unsigned short*)sh.st.A + chunk * 512);
            GLOAD_LDS16(W + (size_t)(n0 + row) * D_MODEL + k0 + sgr * 8,
                        (unsigned short*)sh.st.W + chunk * 512);
        }
        __syncthreads();
#pragma unroll
        for (int kb = 0; kb < 2; ++kb) {
            short8 af[4], bf[4];
#pragma unroll
            for (int mi = 0; mi < 4; ++mi) {
                const int row = wr + mi * 16 + fr;
                af[mi] = *(const short8*)(sh.st.A + row * 64 +
                                          (((kb * 4 + g) ^ (fr & 7)) * 8));
            }
#pragma unroll
            for (int ni = 0; ni < 4; ++ni) {
                const int row = wc + ni * 16 + fr;
                bf[ni] = *(const short8*)(sh.st.W + row * 64 +
                                          (((kb * 4 + g) ^ (fr & 7)) * 8));
            }
#pragma unroll
            for (int mi = 0; mi < 4; ++mi)
#pragma unroll
                for (int ni = 0; ni < 4; ++ni)
                    acc[mi][ni] = __builtin_amdgcn_mfma_f32_16x16x32_bf16(af[mi], bf[ni],
                                                                          acc[mi][ni], 0, 0, 0);
        }
        __syncthreads();
    }

    const int ro = g * 4;   // C-layout row base
    if (z < 2) {
        // Q/K: bounce acc through LDS -> wave writes 1KB contiguous per rep
        unsigned short* outp = (z == 0) ? O0 : O1;
#pragma unroll
        for (int mi = 0; mi < 4; ++mi)
#pragma unroll
            for (int ni = 0; ni < 4; ++ni)
#pragma unroll
                for (int r = 0; r < 4; ++r)
                    sh.vb[ww][(mi * 16 + ro + r) * 72 + ni * 16 + fr] = f2bf(acc[mi][ni][r]);
        // same-wave buffer: DS in-order, no barrier needed
        const int hh = (n0 + wc) >> 6;           // wave's 64-col quadrant = one head
        const int colb = (lane & 7) * 8;
#pragma unroll
        for (int rep = 0; rep < 8; ++rep) {
            const int rl = rep * 8 + (lane >> 3);          // local row 0..63
            const int m = m0 + wr + rl;
            const int b = m >> 11, t = m & (T_SEQ - 1);
            short8 vv = *(const short8*)(&sh.vb[ww][rl * 72 + colb]);
            *(short8*)(outp + ((size_t)(b * N_HEADS + hh) * T_SEQ + t) * HEAD_W + colb) = vv;
        }
    } else {
        // V: transpose through per-wave LDS bounce, coalesced 16B stores
#pragma unroll
        for (int mi = 0; mi < 4; ++mi)
#pragma unroll
            for (int ni = 0; ni < 4; ++ni)
#pragma unroll
                for (int r = 0; r < 4; ++r)
                    sh.vb[ww][(ni * 16 + fr) * 72 + mi * 16 + ro + r] = f2bf(acc[mi][ni][r]);
        // same-wave buffer: DS in-order, no barrier needed
#pragma unroll
        for (int rep = 0; rep < 8; ++rep) {
            const int nl = rep * 8 + (lane >> 3);          // row within wave quadrant (n)
            const int n = n0 + wc + nl;
            const int h = n >> 6, wd = n & (HEAD_W - 1);
            const int m = m0 + wr + (lane & 7) * 8;        // 8 consecutive t
            const int b = m >> 11, t = m & (T_SEQ - 1);
            short8 vv = *(const short8*)(&sh.vb[ww][nl * 72 + (lane & 7) * 8]);
            *(short8*)(O2 + ((size_t)(b * N_HEADS + h) * HEAD_W + wd) * T_SEQ + t) = vv;
        }
    }
}

// ---------------- flash attention fwd, causal + ALiBi, fixed-reference softmax ----------------
// R23 (= R22 + mask fix): 128-q items (qi in [0,16), q0=qi*128, t_hi=2qi+1). Each wave owns
// 32 q-rows as two 16-row Q-tiles (qt=0,1); kf/vf LDS reads hoisted across qt -> per-q LDS
// traffic halves, staging+barriers amortized 2x. Grid 1024 = 4 blocks/CU -> entire grid
// co-resident, one generation. Split-K: ck0=[t_hi-15,t_hi](diag), ck1a=[t_hi-23,t_hi-16],
// ck1b=[t_lo,t_hi-24]. Bias folded into MFMA C-init (separable). setprio around MFMA.
// BUG FIX vs R22: causal ri now includes -g*4 (lane holds k = ct*16 + g*4 + r).
__global__ __launch_bounds__(256, 4) void attn_fwd(const unsigned short* __restrict__ Qb,
                                                   const unsigned short* __restrict__ Kb,
                                                   const unsigned short* __restrict__ Vtb,
                                                   float* __restrict__ outp,
                                                   unsigned short* __restrict__ opart,
                                                   float* __restrict__ lpart) {
    __shared__ unsigned short Kl[2][64 * 64];    // [kv-row][d], granule ^= row&7
    __shared__ unsigned short Vl[2][64 * 64];    // [d][kv],   granule ^= d&7

    const int bid = blockIdx.x;                  // 1024 blocks
    int ib, ck;                                  // ck: 0 = chunk0/single, 1 = chunk1a, 2 = chunk1b
    if (bid < 512)      { ck = 0; ib = bid; }            // qi 15..0
    else if (bid < 768) { ck = 1; ib = bid - 512; }      // qi 15..8
    else                { ck = 2; ib = bid - 768; }      // qi 15..8
    const int qi = 15 - (ib >> 5);
    const int b = (ib >> 4) & 1;
    const int h = ((ib & 15) + 5 * (ib >> 8)) & 15;
    const int q0 = qi * 128;
    const int tid = threadIdx.x, lane = tid & 63, w = tid >> 6;
    const int qw = q0 + w * 32;                  // wave's first q-row (qt=0 tile)
    const float slope2 = exp2f(-0.5f * (float)(h + 1)) * LOG2E;

    // static dead-tile window: keep tile t iff slope2*(t*64+63 - q0) >= -40
    const float tlf = ((float)q0 - 63.0f - 40.0f / slope2) * 0.015625f;
    const int t_lo = (tlf > 0.0f) ? (int)ceilf(tlf) : 0;
    const int t_hi = 2 * qi + 1;

    const bool single = (t_lo > t_hi - 16);      // whole live window fits in ck0
    int t_start, t_end;
    if (ck == 0) {
        t_start = t_hi;
        t_end = single ? t_lo : (t_hi - 15);
    } else if (ck == 1) {
        t_start = t_hi - 16;
        t_end = (t_lo > t_hi - 23) ? t_lo : (t_hi - 23);
        if (t_start < t_end) return;             // empty (covers single case too)
    } else {
        t_start = t_hi - 24;
        t_end = t_lo;
        if (t_start < t_end) return;             // empty
    }
    const int slot = (((qi - 8) << 5) | (h << 1) | b) + (ck << 8);  // +256 per chunk level

    const unsigned short* Qp = Qb + (size_t)(b * N_HEADS + h) * T_SEQ * HEAD_W;
    const unsigned short* Kp = Kb + (size_t)(b * N_HEADS + h) * T_SEQ * HEAD_W;
    const unsigned short* Vp = Vtb + (size_t)(b * N_HEADS + h) * HEAD_W * T_SEQ;

    const int g = lane >> 4, c = lane & 15;
    const int srow = lane >> 3;                  // staging row-in-chunk 0..7
    const int sgr = (lane & 7) ^ srow;           // pre-swizzled source granule
    const bool ghi = (g >= 2);

#define STAGE_KV(buf, k0_)                                                               \
    {                                                                                    \
        _Pragma("unroll")                                                                \
        for (int it = 0; it < 2; ++it) {                                                 \
            const int ch = w * 2 + it;                                                   \
            const int row = ch * 8 + srow;                                               \
            GLOAD_LDS16(Kp + (size_t)((k0_) + row) * HEAD_W + sgr * 8,                   \
                        (unsigned short*)Kl[buf] + ch * 512);                            \
            GLOAD_LDS16(Vp + (size_t)row * T_SEQ + (k0_) + sgr * 8,                      \
                        (unsigned short*)Vl[buf] + ch * 512);                            \
        }                                                                                \
    }

    // Q fragments (B-operand): lane holds Q[q=qw+qt*16+c][kb*32 + g*8 + j]
    short8 qf[2][2];
#pragma unroll
    for (int qt = 0; qt < 2; ++qt)
#pragma unroll
        for (int kb = 0; kb < 2; ++kb)
            qf[qt][kb] = *(const short8*)(Qp + (size_t)(qw + qt * 16 + c) * HEAD_W +
                                          kb * 32 + g * 8);

    // separable bias + reference (qt=0 rows): bias = ctp[ct] + rp4[r] + utq
    float ctp[4], rp4[4];
#pragma unroll
    for (int ct = 0; ct < 4; ++ct) ctp[ct] = slope2 * (float)(ct * 16);
#pragma unroll
    for (int r = 0; r < 4; ++r)
        rp4[r] = slope2 * (float)(g * 4 + r - qw - c) - 30.0f;
    const float sl16 = slope2 * 16.0f;
    const int maskthr = 2 * qi + (w >> 1);       // first tile needing causal handling

    union { uint32_t u[4]; short8 s8; } one_u;
#pragma unroll
    for (int i = 0; i < 4; ++i) one_u.u[i] = 0x3F803F80u;   // bf16 1.0 pairs
    const short8 ones8 = one_u.s8;

    f32x4 o[2][4];
    f32x4 lac[2];
#pragma unroll
    for (int qt = 0; qt < 2; ++qt) {
        lac[qt] = (f32x4){0.f, 0.f, 0.f, 0.f};
#pragma unroll
        for (int i = 0; i < 4; ++i) o[qt][i] = (f32x4){0.f, 0.f, 0.f, 0.f};
    }

    STAGE_KV(t_start & 1, t_start * 64);
    __syncthreads();

    for (int t = t_start; t >= t_end; --t) {
        const int k0 = t * 64;
        if (t > t_end) STAGE_KV((t - 1) & 1, k0 - 64);   // in flight under compute
        const unsigned short* Kt = Kl[t & 1];
        const unsigned short* Vt = Vl[t & 1];
        const float ut = slope2 * (float)k0;

        // ---- S^T = K Q^T + bias (both qt), kf shared across qt ----
        f32x4 s[2][4];
#pragma unroll
        for (int qt = 0; qt < 2; ++qt) {
            const float utq = ut - sl16 * (float)qt;
#pragma unroll
            for (int ct = 0; ct < 4; ++ct)
#pragma unroll
                for (int r = 0; r < 4; ++r) s[qt][ct][r] = ctp[ct] + (rp4[r] + utq);
        }
        __builtin_amdgcn_s_setprio(1);
#pragma unroll
        for (int ct = 0; ct < 4; ++ct)
#pragma unroll
            for (int kb = 0; kb < 2; ++kb) {
                const short8 kf = *(const short8*)(Kt + (ct * 16 + c) * 64 +
                                                   (((kb * 4 + g) ^ (c & 7)) * 8));
                s[0][ct] = __builtin_amdgcn_mfma_f32_16x16x32_bf16(kf, qf[0][kb],
                                                                   s[0][ct], 0, 0, 0);
                s[1][ct] = __builtin_amdgcn_mfma_f32_16x16x32_bf16(kf, qf[1][kb],
                                                                   s[1][ct], 0, 0, 0);
            }
        __builtin_amdgcn_s_setprio(0);

        // ---- causal mask (diagonal / dead tiles near t_hi) + P = exp2(s) + pack ----
        union { uint32_t u[4]; short8 s8; } pa[2][2];
#pragma unroll
        for (int qt = 0; qt < 2; ++qt) {
            if (t >= maskthr) {   // wave-uniform; handles diagonal AND fully-masked tiles
                // lane holds k = ct*16 + g*4 + r, q = qw + qt*16 + c: mask iff k > q - k0
                const int ri = qw + qt * 16 + c - k0 - g * 4;
#pragma unroll
                for (int ct = 0; ct < 4; ++ct)
#pragma unroll
                    for (int r = 0; r < 4; ++r)
                        s[qt][ct][r] = (ct * 16 + r > ri) ? -1e30f : s[qt][ct][r];
            }
            uint32_t pk[4][2];
#pragma unroll
            for (int ct = 0; ct < 4; ++ct) {
                float p[4];
#pragma unroll
                for (int r = 0; r < 4; ++r) p[r] = exp2f(s[qt][ct][r]);
                pk[ct][0] = cvt_pk_bf16(p[0], p[1]);
                pk[ct][1] = cvt_pk_bf16(p[2], p[3]);
            }
            // in-register redistribute to A-fragment layout
#pragma unroll
            for (int kb = 0; kb < 2; ++kb)
#pragma unroll
                for (int v = 0; v < 2; ++v) {
                    const uint32_t s0v = ghi ? pk[2 * kb + 1][v] : pk[2 * kb][v];
                    const uint32_t s1v = ghi ? pk[2 * kb][v]     : pk[2 * kb + 1][v];
                    const uint32_t x16 = __shfl_xor(s0v, 16);
                    const uint32_t x32 = __shfl_xor(s1v, 32);
                    const uint32_t x48 = __shfl_xor(s1v, 48);
                    pa[qt][kb].u[v]     = (g == 0) ? s0v : (g == 1) ? x48 :
                                          (g == 2) ? x32 : x16;
                    pa[qt][kb].u[2 + v] = (g == 0) ? x16 : (g == 1) ? x32 :
                                          (g == 2) ? x48 : s0v;
                }
        }

        // ---- O += P V (both qt), vf shared across qt; l via mfma(P, ones) ----
        __builtin_amdgcn_s_setprio(1);
#pragma unroll
        for (int kb = 0; kb < 2; ++kb)
#pragma unroll
            for (int db = 0; db < 4; ++db) {
                const short8 vf = *(const short8*)(Vt + (db * 16 + c) * 64 +
                                                   (((kb * 4 + g) ^ (c & 7)) * 8));
                o[0][db] = __builtin_amdgcn_mfma_f32_16x16x32_bf16(pa[0][kb].s8, vf,
                                                                   o[0][db], 0, 0, 0);
                o[1][db] = __builtin_amdgcn_mfma_f32_16x16x32_bf16(pa[1][kb].s8, vf,
                                                                   o[1][db], 0, 0, 0);
            }
#pragma unroll
        for (int kb = 0; kb < 2; ++kb) {
            lac[0] = __builtin_amdgcn_mfma_f32_16x16x32_bf16(pa[0][kb].s8, ones8,
                                                             lac[0], 0, 0, 0);
            lac[1] = __builtin_amdgcn_mfma_f32_16x16x32_bf16(pa[1][kb].s8, ones8,
                                                             lac[1], 0, 0, 0);
        }
        __builtin_amdgcn_s_setprio(0);
        __syncthreads();   // drains next-tile staging + this-tile LDS reads
    }

    if (single) {
        // ---- direct epilogue: rows q = qw + qt*16 + g*4 + r ----
#pragma unroll
        for (int qt = 0; qt < 2; ++qt) {
            float linv[4];
#pragma unroll
            for (int r = 0; r < 4; ++r) linv[r] = 1.0f / lac[qt][r];
#pragma unroll
            for (int db = 0; db < 4; ++db)
#pragma unroll
                for (int r = 0; r < 4; ++r)
                    outp[((size_t)b * T_SEQ + qw + qt * 16 + g * 4 + r) * D_MODEL +
                         h * HEAD_W + db * 16 + c] = o[qt][db][r] * linv[r];
        }
    } else {
        // ---- partial epilogue: o as bf16 (coalesced u64), l as f32 ----
        uint64_t* op64 = (uint64_t*)(opart + (size_t)slot * 8192 + tid * 32);
#pragma unroll
        for (int qt = 0; qt < 2; ++qt)
#pragma unroll
            for (int db = 0; db < 4; ++db) {
                const uint32_t lo = cvt_pk_bf16(o[qt][db][0], o[qt][db][1]);
                const uint32_t hi = cvt_pk_bf16(o[qt][db][2], o[qt][db][3]);
                op64[qt * 4 + db] = (uint64_t)lo | ((uint64_t)hi << 32);
            }
        if (c == 0) {
#pragma unroll
            for (int qt = 0; qt < 2; ++qt)
                *(f32x4*)(lpart + slot * 128 + w * 32 + qt * 16 + g * 4) = lac[qt];
        }
    }
#undef STAGE_KV
}

// ---------------- reduce: combine ck0/1a/1b partials, normalize, write output ----------
__global__ __launch_bounds__(256) void attn_reduce(const unsigned short* __restrict__ opart,
                                                   const float* __restrict__ lpart,
                                                   float* __restrict__ outp) {
    const int bid = blockIdx.x;             // 256 deep-candidate items (qi in [8,16))
    const int qi = 8 + (bid >> 5);
    const int h = (bid >> 1) & 15;
    const int b = bid & 1;
    const float slope2 = exp2f(-0.5f * (float)(h + 1)) * LOG2E;
    const int q0 = qi * 128;
    const float tlf = ((float)q0 - 63.0f - 40.0f / slope2) * 0.015625f;  // must match attn_fwd
    const int t_lo = (tlf > 0.0f) ? (int)ceilf(tlf) : 0;
    if (t_lo > 2 * qi - 15) return;         // single item (t_lo > t_hi-16) -> ck0 wrote direct
    const bool has1b = (t_lo <= 2 * qi - 23);   // ck1b produced a partial (t_lo <= t_hi-24)

    const int key = ((qi - 8) << 5) | (h << 1) | b;
    const int tid = threadIdx.x, lane = tid & 63, w = tid >> 6;
    const int g = lane >> 4, c = lane & 15;

    const uint64_t* p0 = (const uint64_t*)(opart + (size_t)key * 8192 + tid * 32);
    const uint64_t* p1 = (const uint64_t*)(opart + (size_t)(key + 256) * 8192 + tid * 32);
    const uint64_t* p2 = (const uint64_t*)(opart + (size_t)(key + 512) * 8192 + tid * 32);

#pragma unroll
    for (int qt = 0; qt < 2; ++qt) {
        const int rowb = w * 32 + qt * 16 + g * 4;
        float linv[4];
#pragma unroll
        for (int r = 0; r < 4; ++r) {
            float lsum = lpart[key * 128 + rowb + r] + lpart[(key + 256) * 128 + rowb + r];
            if (has1b) lsum += lpart[(key + 512) * 128 + rowb + r];
            linv[r] = 1.0f / lsum;
        }
#pragma unroll
        for (int db = 0; db < 4; ++db) {
            const uint64_t a = p0[qt * 4 + db];
            const uint64_t bb = p1[qt * 4 + db];
            const uint64_t cc = has1b ? p2[qt * 4 + db] : 0ull;
#pragma unroll
            for (int r = 0; r < 4; ++r) {
                float s = bf2f((uint32_t)((a >> (16 * r)) & 0xFFFFu)) +
                          bf2f((uint32_t)((bb >> (16 * r)) & 0xFFFFu));
                if (has1b) s += bf2f((uint32_t)((cc >> (16 * r)) & 0xFFFFu));
                outp[((size_t)b * T_SEQ + q0 + rowb + r) * D_MODEL + h * HEAD_W +
                     db * 16 + c] = s * linv[r];
            }
        }
    }
}

// ---------------- launch ----------------
extern "C" void kernel_launch(void* const* d_in, const int* in_sizes, int n_in,
                              void* d_out, int out_size, void* d_ws, size_t ws_size,
                              hipStream_t stream) {
    const float* x  = (const float*)d_in[0];
    // d_in[1] = additive causal mask, applied analytically -> unused
    const float* Wq = (const float*)d_in[2];
    const float* Wk = (const float*)d_in[3];
    const float* Wv = (const float*)d_in[4];
    float* out = (float*)d_out;

    uint8_t* ws = (uint8_t*)d_ws;
    unsigned short* xb  = (unsigned short*)(ws);              // 8 MB  x bf16 [4096,1024]
    unsigned short* wqb = (unsigned short*)(ws + 8388608);    // 2 MB  Wq * (log2e/8)
    unsigned short* wkb = (unsigned short*)(ws + 10485760);   // 2 MB
    unsigned short* wvb = (unsigned short*)(ws + 12582912);   // 2 MB
    unsigned short* Qb  = (unsigned short*)(ws + 14680064);   // 8 MB  [b,h,t,w]
    unsigned short* Kb  = (unsigned short*)(ws + 23068672);   // 8 MB  [b,h,t,w]
    unsigned short* Vtb = (unsigned short*)(ws + 31457280);   // 8 MB  [b,h,w,t]
    // after qkv_gemm, xb/wqb/wkb/wvb (14 MB) are dead -> reuse for split-K partials:
    unsigned short* opart = (unsigned short*)(ws);            // 768 slots x 8192 bf16 = 12.58 MB
    float*          lpart = (float*)(ws + 12582912);          // 768 slots x 128 f32 = 384 KB

    cvt_fused<<<7168, 256, 0, stream>>>((const float4*)x, (const float4*)Wq,
                                        (const float4*)Wk, (const float4*)Wv,
                                        (uint64_t*)xb, (uint64_t*)wqb,
                                        (uint64_t*)wkb, (uint64_t*)wvb);

    qkv_gemm<<<768, 256, 0, stream>>>(xb, wqb, wkb, wvb, Qb, Kb, Vtb);

    attn_fwd<<<1024, 256, 0, stream>>>(Qb, Kb, Vtb, out, opart, lpart);
    attn_reduce<<<256, 256, 0, stream>>>(opart, lpart, out);
}

// Round 24
// 77.687 us; speedup vs baseline: 1.2825x; 1.2825x over previous
//
#include <hip/hip_runtime.h>
#include <stdint.h>

#define N_B 2
#define T_SEQ 2048
#define D_MODEL 1024
#define N_HEADS 16
#define HEAD_W 64

typedef __attribute__((ext_vector_type(8))) short short8;
typedef __attribute__((ext_vector_type(4))) float f32x4;

// async global->LDS, 16B per lane; LDS dst is wave-uniform base (HW adds lane*16)
#define GLOAD_LDS16(gp, lp)                                                          \
    __builtin_amdgcn_global_load_lds((__attribute__((address_space(1))) void*)(gp),  \
                                     (__attribute__((address_space(3))) void*)(lp),  \
                                     16, 0, 0)

__device__ __forceinline__ unsigned short f2bf(float f) {
    union { float f; uint32_t u; } cv; cv.f = f;
    return (unsigned short)((cv.u + 0x7fffu + ((cv.u >> 16) & 1u)) >> 16);  // RNE
}

__device__ __forceinline__ uint32_t cvt_pk_bf16(float lo, float hi) {
    uint32_t r;
    asm("v_cvt_pk_bf16_f32 %0, %1, %2" : "=v"(r) : "v"(lo), "v"(hi));
    return r;
}

__device__ __forceinline__ float bf2f(uint32_t us) {
    union { uint32_t u; float f; } cv; cv.u = us << 16; return cv.f;
}

#define LOG2E 1.44269504f

// ---------------- fused f32 -> bf16 converts (x, Wq*scale, Wk, Wv) ----------------
__global__ __launch_bounds__(256) void cvt_fused(const float4* __restrict__ x,
                                                 const float4* __restrict__ wq,
                                                 const float4* __restrict__ wk,
                                                 const float4* __restrict__ wv,
                                                 uint64_t* __restrict__ xb,
                                                 uint64_t* __restrict__ wqb,
                                                 uint64_t* __restrict__ wkb,
                                                 uint64_t* __restrict__ wvb) {
    const int i = blockIdx.x * 256 + threadIdx.x;   // 1835008 total float4s
    const float4* src; uint64_t* dst; float scale; int off;
    if (i < 1048576)      { src = x;  dst = xb;  scale = 1.f;            off = i; }
    else if (i < 1310720) { src = wq; dst = wqb; scale = 0.125f * LOG2E; off = i - 1048576; }
    else if (i < 1572864) { src = wk; dst = wkb; scale = 1.f;            off = i - 1310720; }
    else                  { src = wv; dst = wvb; scale = 1.f;            off = i - 1572864; }
    float4 v = src[off];
    union { unsigned short us[4]; uint64_t u64; } o;
    o.us[0] = f2bf(v.x * scale);
    o.us[1] = f2bf(v.y * scale);
    o.us[2] = f2bf(v.z * scale);
    o.us[3] = f2bf(v.w * scale);
    dst[off] = o.u64;
}

// ---------------- QKV projection GEMM (flattened grid + XCD swizzle, BK=64) ----------------
// C[m,n] = sum_k A[m,k]*W[n,k]   [proven 128x128 tile; 128x64 regressed (R13)]
// __launch_bounds__(256,4): 4 blocks/CU (R18/R19 proved occupancy was binding; fits, no spill).
// All three outputs use the per-wave LDS bounce -> coalesced 16B stores:
// z=0: Q -> [b,h,t,w]; z=1: K -> [b,h,t,w]; z=2: V -> [b,h,w,t] (transposed)
__global__ __launch_bounds__(256, 4) void qkv_gemm(const unsigned short* __restrict__ A,
                                                   const unsigned short* __restrict__ W0,
                                                   const unsigned short* __restrict__ W1,
                                                   const unsigned short* __restrict__ W2,
                                                   unsigned short* __restrict__ O0,
                                                   unsigned short* __restrict__ O1,
                                                   unsigned short* __restrict__ O2) {
    __shared__ union {
        struct { unsigned short A[128 * 64]; unsigned short W[128 * 64]; } st;
        unsigned short vb[4][64 * 72];   // epilogue bounce (padded rows, 144B)
    } sh;
    // XCD-aware bijective swizzle: each XCD sweeps one column of tiles (W-panel L2-resident)
    const int bid0 = blockIdx.x;                       // 768 blocks
    const int bid = (bid0 & 7) * 96 + (bid0 >> 3);     // bijective: 768 = 8*96
    const int z = bid >> 8;
    const int rem = bid & 255;
    const int m0 = (rem >> 3) * 128;
    const int n0 = (rem & 7) * 128;
    const unsigned short* W = (z == 0) ? W0 : (z == 1) ? W1 : W2;
    const int tid = threadIdx.x;
    const int lane = tid & 63;
    const int ww = tid >> 6;
    const int wr = (ww >> 1) * 64;
    const int wc = (ww & 1) * 64;
    const int g = lane >> 4;             // k-granule 0..3 within 32-k chunk
    const int fr = lane & 15;
    const int srow = lane >> 3;          // staging row-in-chunk 0..7 (8 rows x 128B per 1KB)
    const int sgr = (lane & 7) ^ srow;   // pre-swizzled source granule (granule ^= row&7)

    f32x4 acc[4][4];
#pragma unroll
    for (int i = 0; i < 4; ++i)
#pragma unroll
        for (int j = 0; j < 4; ++j) acc[i][j] = (f32x4){0.f, 0.f, 0.f, 0.f};

    for (int k0 = 0; k0 < D_MODEL; k0 += 64) {
#pragma unroll
        for (int it = 0; it < 4; ++it) {
            const int chunk = ww * 4 + it;          // 0..15, each 8 rows x 64 shorts
            const int row = chunk * 8 + srow;       // 0..127
            GLOAD_LDS16(A + (size_t)(m0 + row) * D_MODEL + k0 + sgr * 8,
                        (unsigned short*)sh.st.A + chunk * 512);
            GLOAD_LDS16(W + (size_t)(n0 + row) * D_MODEL + k0 + sgr * 8,
                        (unsigned short*)sh.st.W + chunk * 512);
        }
        __syncthreads();
#pragma unroll
        for (int kb = 0; kb < 2; ++kb) {
            short8 af[4], bf[4];
#pragma unroll
            for (int mi = 0; mi < 4; ++mi) {
                const int row = wr + mi * 16 + fr;
                af[mi] = *(const short8*)(sh.st.A + row * 64 +
                                          (((kb * 4 + g) ^ (fr & 7)) * 8));
            }
#pragma unroll
            for (int ni = 0; ni < 4; ++ni) {
                const int row = wc + ni * 16 + fr;
                bf[ni] = *(const short8*)(sh.st.W + row * 64 +
                                          (((kb * 4 + g) ^ (fr & 7)) * 8));
            }
#pragma unroll
            for (int mi = 0; mi < 4; ++mi)
#pragma unroll
                for (int ni = 0; ni < 4; ++ni)
                    acc[mi][ni] = __builtin_amdgcn_mfma_f32_16x16x32_bf16(af[mi], bf[ni],
                                                                          acc[mi][ni], 0, 0, 0);
        }
        __syncthreads();
    }

    const int ro = g * 4;   // C-layout row base
    if (z < 2) {
        // Q/K: bounce acc through LDS -> wave writes 1KB contiguous per rep
        unsigned short* outp = (z == 0) ? O0 : O1;
#pragma unroll
        for (int mi = 0; mi < 4; ++mi)
#pragma unroll
            for (int ni = 0; ni < 4; ++ni)
#pragma unroll
                for (int r = 0; r < 4; ++r)
                    sh.vb[ww][(mi * 16 + ro + r) * 72 + ni * 16 + fr] = f2bf(acc[mi][ni][r]);
        // same-wave buffer: DS in-order, no barrier needed
        const int hh = (n0 + wc) >> 6;           // wave's 64-col quadrant = one head
        const int colb = (lane & 7) * 8;
#pragma unroll
        for (int rep = 0; rep < 8; ++rep) {
            const int rl = rep * 8 + (lane >> 3);          // local row 0..63
            const int m = m0 + wr + rl;
            const int b = m >> 11, t = m & (T_SEQ - 1);
            short8 vv = *(const short8*)(&sh.vb[ww][rl * 72 + colb]);
            *(short8*)(outp + ((size_t)(b * N_HEADS + hh) * T_SEQ + t) * HEAD_W + colb) = vv;
        }
    } else {
        // V: transpose through per-wave LDS bounce, coalesced 16B stores
#pragma unroll
        for (int mi = 0; mi < 4; ++mi)
#pragma unroll
            for (int ni = 0; ni < 4; ++ni)
#pragma unroll
                for (int r = 0; r < 4; ++r)
                    sh.vb[ww][(ni * 16 + fr) * 72 + mi * 16 + ro + r] = f2bf(acc[mi][ni][r]);
        // same-wave buffer: DS in-order, no barrier needed
#pragma unroll
        for (int rep = 0; rep < 8; ++rep) {
            const int nl = rep * 8 + (lane >> 3);          // row within wave quadrant (n)
            const int n = n0 + wc + nl;
            const int h = n >> 6, wd = n & (HEAD_W - 1);
            const int m = m0 + wr + (lane & 7) * 8;        // 8 consecutive t
            const int b = m >> 11, t = m & (T_SEQ - 1);
            short8 vv = *(const short8*)(&sh.vb[ww][nl * 72 + (lane & 7) * 8]);
            *(short8*)(O2 + ((size_t)(b * N_HEADS + h) * HEAD_W + wd) * T_SEQ + t) = vv;
        }
    }
}

// ---------------- flash attention fwd, causal + ALiBi, fixed-reference softmax ----------------
// R6 engine (gload_lds dbuf swizzled LDS, P=exp2(s+bias-30), l via mfma(P,ones)).
// 3-way split-K for deep items (qi>=16): chunk0 = [qi-15, qi] (16, diagonal),
// chunk1a = [max(t_lo,qi-23), qi-16] (<=8), chunk1b = [t_lo, qi-24] (<=8, often empty).
// Dispatch [chunk0 | shallow | chunk1a | chunk1b]; T5 setprio around MFMA clusters (R20 +1.1us).
// ALiBi bias + reference folded into the QK^T MFMA C-initializer (R21 +0.9us).
// [R16: finer split regressed; R23: denser 2-Q-tile blocks regressed -> this granularity
// is the measured optimum of the family in both directions.]
// Fixed reference -> partials purely additive; attn_reduce sums up to 3 partials.
__global__ __launch_bounds__(256, 5) void attn_fwd(const unsigned short* __restrict__ Qb,
                                                   const unsigned short* __restrict__ Kb,
                                                   const unsigned short* __restrict__ Vtb,
                                                   float* __restrict__ outp,
                                                   unsigned short* __restrict__ opart,
                                                   float* __restrict__ lpart) {
    __shared__ unsigned short Kl[2][64 * 64];    // [kv-row][d], granule ^= row&7
    __shared__ unsigned short Vl[2][64 * 64];    // [d][kv],   granule ^= d&7

    const int bid = blockIdx.x;                  // 2048 blocks
    int ib, ck;                                  // ck: 0 = chunk0/shallow, 1 = chunk1a, 2 = chunk1b
    if (bid < 1024)      { ck = 0; ib = bid; }
    else if (bid < 1536) { ck = 1; ib = bid - 1024; }   // ib in [0,512) -> qi in 16..31
    else                 { ck = 2; ib = bid - 1536; }
    // decode: qi descending (heavy first); h rotated by +5 per 256-ib generation
    const int qi = 31 - (ib >> 5);
    const int b = (ib >> 4) & 1;
    const int h = ((ib & 15) + 5 * (ib >> 8)) & 15;
    const int q0 = qi * 64;
    const int tid = threadIdx.x, lane = tid & 63, w = tid >> 6;
    const int qw = q0 + w * 16;
    const float slope2 = exp2f(-0.5f * (float)(h + 1)) * LOG2E;

    // static dead-tile window: keep tile t iff slope2*(t*64+63 - q0) >= -40
    const float tlf = ((float)q0 - 63.0f - 40.0f / slope2) * 0.015625f;
    const int t_lo = (tlf > 0.0f) ? (int)ceilf(tlf) : 0;

    const bool deep = (qi >= 16);
    const bool single = !deep || (t_lo > qi - 16);   // whole live window fits in chunk0
    int t_start, t_end;
    if (ck == 0) {
        t_start = qi;
        t_end = single ? t_lo : (qi - 15);
    } else if (ck == 1) {
        t_start = qi - 16;
        t_end = (t_lo > qi - 23) ? t_lo : (qi - 23);
        if (t_start < t_end) return;                 // empty (covers single case too)
    } else {
        t_start = qi - 24;
        t_end = t_lo;
        if (t_start < t_end) return;                 // empty
    }
    const int slot = (((qi - 16) << 5) | (h << 1) | b) + (ck << 9);  // +512 per chunk level

    const unsigned short* Qp = Qb + (size_t)(b * N_HEADS + h) * T_SEQ * HEAD_W;
    const unsigned short* Kp = Kb + (size_t)(b * N_HEADS + h) * T_SEQ * HEAD_W;
    const unsigned short* Vp = Vtb + (size_t)(b * N_HEADS + h) * HEAD_W * T_SEQ;

    const int g = lane >> 4, c = lane & 15;
    const int srow = lane >> 3;                  // staging row-in-chunk 0..7
    const int sgr = (lane & 7) ^ srow;           // pre-swizzled source granule
    const bool ghi = (g >= 2);

#define STAGE_KV(buf, k0_)                                                               \
    {                                                                                    \
        _Pragma("unroll")                                                                \
        for (int it = 0; it < 2; ++it) {                                                 \
            const int ch = w * 2 + it;                                                   \
            const int row = ch * 8 + srow;                                               \
            GLOAD_LDS16(Kp + (size_t)((k0_) + row) * HEAD_W + sgr * 8,                   \
                        (unsigned short*)Kl[buf] + ch * 512);                            \
            GLOAD_LDS16(Vp + (size_t)row * T_SEQ + (k0_) + sgr * 8,                      \
                        (unsigned short*)Vl[buf] + ch * 512);                            \
        }                                                                                \
    }

    // Q fragments (B-operand): lane holds Q[q=qw+c][kb*32 + g*8 + j]
    short8 qf[2];
#pragma unroll
    for (int kb = 0; kb < 2; ++kb)
        qf[kb] = *(const short8*)(Qp + (size_t)(qw + c) * HEAD_W + kb * 32 + g * 8);

    // hoisted per-lane ALiBi + reference: K16[ct][r] = slope2*(ct*16+g*4+r - qw - c) - 30
    float K16[4][4];
#pragma unroll
    for (int ct = 0; ct < 4; ++ct)
#pragma unroll
        for (int r = 0; r < 4; ++r)
            K16[ct][r] = slope2 * (float)(ct * 16 + g * 4 + r - qw - c) - 30.0f;

    union { uint32_t u[4]; short8 s8; } one_u;
#pragma unroll
    for (int i = 0; i < 4; ++i) one_u.u[i] = 0x3F803F80u;   // bf16 1.0 pairs
    const short8 ones8 = one_u.s8;

    f32x4 o[4];
#pragma unroll
    for (int i = 0; i < 4; ++i) o[i] = (f32x4){0.f, 0.f, 0.f, 0.f};
    f32x4 lac = (f32x4){0.f, 0.f, 0.f, 0.f};   // row-sums, C-layout rows q = qw+g*4+r

    STAGE_KV(t_start & 1, t_start * 64);
    __syncthreads();

    for (int t = t_start; t >= t_end; --t) {
        const int k0 = t * 64;
        if (t > t_end) STAGE_KV((t - 1) & 1, k0 - 64);   // in flight under compute
        const unsigned short* Kt = Kl[t & 1];
        const unsigned short* Vt = Vl[t & 1];

        // ---- S^T = K Q^T + bias : bias folded into the MFMA C-initializer ----
        const float ut = slope2 * (float)k0;
        f32x4 s[4];
#pragma unroll
        for (int ct = 0; ct < 4; ++ct)
#pragma unroll
            for (int r = 0; r < 4; ++r) s[ct][r] = K16[ct][r] + ut;
        __builtin_amdgcn_s_setprio(1);
#pragma unroll
        for (int ct = 0; ct < 4; ++ct)
#pragma unroll
            for (int kb = 0; kb < 2; ++kb) {
                const short8 kf = *(const short8*)(Kt + (ct * 16 + c) * 64 +
                                                   (((kb * 4 + g) ^ (c & 7)) * 8));
                s[ct] = __builtin_amdgcn_mfma_f32_16x16x32_bf16(kf, qf[kb], s[ct], 0, 0, 0);
            }
        __builtin_amdgcn_s_setprio(0);

        if (t == qi) {   // diagonal tile (chunk0 top): causal mask (j > i -> -inf)
            const int ri = w * 16 + c - g * 4;
#pragma unroll
            for (int ct = 0; ct < 4; ++ct)
#pragma unroll
                for (int r = 0; r < 4; ++r)
                    s[ct][r] = (ct * 16 + r > ri) ? -1e30f : s[ct][r];
        }

        // ---- P = exp2(s), packed to bf16 pairs ----
        uint32_t pk[4][2];
#pragma unroll
        for (int ct = 0; ct < 4; ++ct) {
            float p[4];
#pragma unroll
            for (int r = 0; r < 4; ++r)
                p[r] = exp2f(s[ct][r]);
            pk[ct][0] = cvt_pk_bf16(p[0], p[1]);
            pk[ct][1] = cvt_pk_bf16(p[2], p[3]);
        }

        // ---- in-register redistribute to A-fragment layout + PV + l ----
#pragma unroll
        for (int kb = 0; kb < 2; ++kb) {
            uint32_t pu[4];
#pragma unroll
            for (int v = 0; v < 2; ++v) {
                const uint32_t s0v = ghi ? pk[2 * kb + 1][v] : pk[2 * kb][v];
                const uint32_t s1v = ghi ? pk[2 * kb][v]     : pk[2 * kb + 1][v];
                const uint32_t x16 = __shfl_xor(s0v, 16);
                const uint32_t x32 = __shfl_xor(s1v, 32);
                const uint32_t x48 = __shfl_xor(s1v, 48);
                pu[v]     = (g == 0) ? s0v : (g == 1) ? x48 : (g == 2) ? x32 : x16;
                pu[2 + v] = (g == 0) ? x16 : (g == 1) ? x32 : (g == 2) ? x48 : s0v;
            }
            union { uint32_t u[4]; short8 s8; } pa;
            pa.u[0] = pu[0]; pa.u[1] = pu[1]; pa.u[2] = pu[2]; pa.u[3] = pu[3];
            __builtin_amdgcn_s_setprio(1);
#pragma unroll
            for (int db = 0; db < 4; ++db) {
                const short8 vf = *(const short8*)(Vt + (db * 16 + c) * 64 +
                                                   (((kb * 4 + g) ^ (c & 7)) * 8));
                o[db] = __builtin_amdgcn_mfma_f32_16x16x32_bf16(pa.s8, vf, o[db], 0, 0, 0);
            }
            lac = __builtin_amdgcn_mfma_f32_16x16x32_bf16(pa.s8, ones8, lac, 0, 0, 0);
            __builtin_amdgcn_s_setprio(0);
        }
        __syncthreads();   // drains next-tile staging + this-tile LDS reads
    }

    if (single) {
        // ---- direct epilogue: o[db][r] = O[q=qw+g*4+r][d=db*16+c]; lac[r] same-row sum ----
        float linv[4];
#pragma unroll
        for (int r = 0; r < 4; ++r) linv[r] = 1.0f / lac[r];
#pragma unroll
        for (int db = 0; db < 4; ++db)
#pragma unroll
            for (int r = 0; r < 4; ++r)
                outp[((size_t)b * T_SEQ + qw + g * 4 + r) * D_MODEL + h * HEAD_W + db * 16 + c] =
                    o[db][r] * linv[r];
    } else {
        // ---- partial epilogue: o as bf16 in fragment order (coalesced u64), l as f32 ----
        uint64_t* op64 = (uint64_t*)(opart + (size_t)slot * 4096 + tid * 16);
#pragma unroll
        for (int db = 0; db < 4; ++db) {
            const uint32_t lo = cvt_pk_bf16(o[db][0], o[db][1]);
            const uint32_t hi = cvt_pk_bf16(o[db][2], o[db][3]);
            op64[db] = (uint64_t)lo | ((uint64_t)hi << 32);
        }
        if (c == 0)
            *(f32x4*)(lpart + slot * 64 + w * 16 + g * 4) = lac;
    }
#undef STAGE_KV
}

// ---------------- reduce: combine chunk0/1a/1b partials, normalize, write output ----------
__global__ __launch_bounds__(256) void attn_reduce(const unsigned short* __restrict__ opart,
                                                   const float* __restrict__ lpart,
                                                   float* __restrict__ outp) {
    const int slot = blockIdx.x;            // 0..511 (qi>=16 items)
    const int qi = 16 + (slot >> 5);
    const int h = (slot & 31) >> 1;
    const int b = slot & 1;
    const float slope2 = exp2f(-0.5f * (float)(h + 1)) * LOG2E;
    const int q0 = qi * 64;
    const float tlf = ((float)q0 - 63.0f - 40.0f / slope2) * 0.015625f;  // must match attn_fwd
    const int t_lo = (tlf > 0.0f) ? (int)ceilf(tlf) : 0;
    if (t_lo > qi - 16) return;             // single-chunk item -> chunk0 wrote out directly
    const bool has1b = (t_lo <= qi - 24);   // chunk1b produced a partial

    const int tid = threadIdx.x, lane = tid & 63, w = tid >> 6;
    const int g = lane >> 4, c = lane & 15;
    const int rowb = w * 16 + g * 4;

    const uint64_t* p0 = (const uint64_t*)(opart + (size_t)slot * 4096 + tid * 16);
    const uint64_t* p1 = (const uint64_t*)(opart + (size_t)(slot + 512) * 4096 + tid * 16);
    const uint64_t* p2 = (const uint64_t*)(opart + (size_t)(slot + 1024) * 4096 + tid * 16);

    float linv[4];
#pragma unroll
    for (int r = 0; r < 4; ++r) {
        float lsum = lpart[slot * 64 + rowb + r] + lpart[(slot + 512) * 64 + rowb + r];
        if (has1b) lsum += lpart[(slot + 1024) * 64 + rowb + r];
        linv[r] = 1.0f / lsum;
    }

#pragma unroll
    for (int db = 0; db < 4; ++db) {
        const uint64_t a = p0[db];
        const uint64_t bb = p1[db];
        const uint64_t cc = has1b ? p2[db] : 0ull;
#pragma unroll
        for (int r = 0; r < 4; ++r) {
            float s = bf2f((uint32_t)((a >> (16 * r)) & 0xFFFFu)) +
                      bf2f((uint32_t)((bb >> (16 * r)) & 0xFFFFu));
            if (has1b) s += bf2f((uint32_t)((cc >> (16 * r)) & 0xFFFFu));
            outp[((size_t)b * T_SEQ + q0 + rowb + r) * D_MODEL + h * HEAD_W + db * 16 + c] =
                s * linv[r];
        }
    }
}

// ---------------- launch ----------------
extern "C" void kernel_launch(void* const* d_in, const int* in_sizes, int n_in,
                              void* d_out, int out_size, void* d_ws, size_t ws_size,
                              hipStream_t stream) {
    const float* x  = (const float*)d_in[0];
    // d_in[1] = additive causal mask, applied analytically -> unused
    const float* Wq = (const float*)d_in[2];
    const float* Wk = (const float*)d_in[3];
    const float* Wv = (const float*)d_in[4];
    float* out = (float*)d_out;

    uint8_t* ws = (uint8_t*)d_ws;
    unsigned short* xb  = (unsigned short*)(ws);              // 8 MB  x bf16 [4096,1024]
    unsigned short* wqb = (unsigned short*)(ws + 8388608);    // 2 MB  Wq * (log2e/8)
    unsigned short* wkb = (unsigned short*)(ws + 10485760);   // 2 MB
    unsigned short* wvb = (unsigned short*)(ws + 12582912);   // 2 MB
    unsigned short* Qb  = (unsigned short*)(ws + 14680064);   // 8 MB  [b,h,t,w]
    unsigned short* Kb  = (unsigned short*)(ws + 23068672);   // 8 MB  [b,h,t,w]
    unsigned short* Vtb = (unsigned short*)(ws + 31457280);   // 8 MB  [b,h,w,t]
    // after qkv_gemm, xb/wqb/wkb/wvb (14 MB) are dead -> reuse for split-K partials:
    unsigned short* opart = (unsigned short*)(ws);            // 1536 slots x 4096 bf16 = 12 MB
    float*          lpart = (float*)(ws + 12582912);          // 1536 slots x 64 f32 = 384 KB

    cvt_fused<<<7168, 256, 0, stream>>>((const float4*)x, (const float4*)Wq,
                                        (const float4*)Wk, (const float4*)Wv,
                                        (uint64_t*)xb, (uint64_t*)wqb,
                                        (uint64_t*)wkb, (uint64_t*)wvb);

    qkv_gemm<<<768, 256, 0, stream>>>(xb, wqb, wkb, wvb, Qb, Kb, Vtb);

    attn_fwd<<<2048, 256, 0, stream>>>(Qb, Kb, Vtb, out, opart, lpart);
    attn_reduce<<<512, 256, 0, stream>>>(opart, lpart, out);
}